// Round 1
// baseline (408.246 us; speedup 1.0000x reference)
//
#include <hip/hip_runtime.h>
#include <hip/hip_bf16.h>

// Problem constants (fixed by the reference):
//   x: [B=1024, N=65536] f32, index: [N] i32 permutation, group size 64.
#define BATCH   1024
#define NEUR    65536
#define GSZ     64
#define NGRP    (NEUR / GSZ)          // 1024 groups
#define F4_PER_ROW (NEUR / 4)         // 16384 float4 per row
#define BLK     1024                  // threads per block (16 waves)
#define ITERS   (F4_PER_ROW / BLK)    // 16 float4 loads per thread

// Build inverse permutation -> group id table: group_of[index[i]] = i / 64.
__global__ void build_group_of(const int* __restrict__ index,
                               int* __restrict__ group_of) {
    int i = blockIdx.x * blockDim.x + threadIdx.x;
    if (i < NEUR) group_of[index[i]] = i >> 6;
}

// One block per batch row. Single pass over x:
//   phase 1: coalesced float4 loads (kept in registers) + LDS atomic group sums
//   phase 2: per-group reciprocal
//   phase 3: multiply register values, coalesced float4 stores
__global__ __launch_bounds__(BLK, 4)
void lateral_norm_kernel(const float* __restrict__ x,
                         const int* __restrict__ group_of,
                         float* __restrict__ out) {
    __shared__ float gsum[NGRP];
    __shared__ float rsum[NGRP];

    const int b = blockIdx.x;
    const int t = threadIdx.x;

    gsum[t] = 0.0f;                    // NGRP == BLK: one entry per thread
    __syncthreads();

    const float4* __restrict__ xrow = (const float4*)(x + (size_t)b * NEUR);
    const int4*   __restrict__ gof  = (const int4*)group_of;

    float4 xv[ITERS];

    #pragma unroll
    for (int it = 0; it < ITERS; ++it) {
        const int e = it * BLK + t;    // float4 index within row — coalesced
        xv[it] = xrow[e];
        const int4 g4 = gof[e];
        unsafeAtomicAdd(&gsum[g4.x], xv[it].x);
        unsafeAtomicAdd(&gsum[g4.y], xv[it].y);
        unsafeAtomicAdd(&gsum[g4.z], xv[it].z);
        unsafeAtomicAdd(&gsum[g4.w], xv[it].w);
    }
    __syncthreads();

    rsum[t] = 1.0f / gsum[t];
    __syncthreads();

    float4* __restrict__ orow = (float4*)(out + (size_t)b * NEUR);

    #pragma unroll
    for (int it = 0; it < ITERS; ++it) {
        const int e = it * BLK + t;
        const int4 g4 = gof[e];        // L1/L2 hit (256 KB table, shared by all rows)
        float4 o;
        o.x = xv[it].x * rsum[g4.x];
        o.y = xv[it].y * rsum[g4.y];
        o.z = xv[it].z * rsum[g4.z];
        o.w = xv[it].w * rsum[g4.w];
        orow[e] = o;
    }
}

extern "C" void kernel_launch(void* const* d_in, const int* in_sizes, int n_in,
                              void* d_out, int out_size, void* d_ws, size_t ws_size,
                              hipStream_t stream) {
    const float* x     = (const float*)d_in[0];
    const int*   index = (const int*)d_in[1];
    float*       out   = (float*)d_out;

    int* group_of = (int*)d_ws;        // 65536 * 4 B = 256 KB of scratch

    build_group_of<<<(NEUR + 255) / 256, 256, 0, stream>>>(index, group_of);
    lateral_norm_kernel<<<BATCH, BLK, 0, stream>>>(x, group_of, out);
}

// Round 3
// 382.553 us; speedup vs baseline: 1.0672x; 1.0672x over previous
//
#include <hip/hip_runtime.h>
#include <hip/hip_bf16.h>

// x: [B=1024, N=65536] f32, index: [N] i32 permutation, group size 64.
#define BATCH   1024
#define NEUR    65536
#define NGRP    1024                  // NEUR / 64 groups
#define BLK     1024                  // threads per block (16 waves)
#define F4_PER_ROW (NEUR / 4)         // 16384 float4 per row
#define ITERS   (F4_PER_ROW / BLK)    // 16 float4 per thread

// Build inverse permutation -> group id table: group_of[index[i]] = i / 64.
__global__ void build_group_of(const int* __restrict__ index,
                               int* __restrict__ group_of) {
    int i = blockIdx.x * blockDim.x + threadIdx.x;
    if (i < NEUR) group_of[index[i]] = i >> 6;
}

// One block per batch row. Row is 256 KB — too big for LDS (R2 lesson) or
// registers (R1 lesson). Instead: two passes over the row, the second served
// by L2/L3 (row is cache-hot right after phase 1; concurrent working set
// ~32 MB << 256 MB L3). Only group sums (4 KB) live in LDS.
__global__ __launch_bounds__(BLK, 8)
void lateral_norm_kernel(const float* __restrict__ x,
                         const int* __restrict__ group_of,
                         float* __restrict__ out) {
    __shared__ float gsum[NGRP];       // 4 KB

    const int b = blockIdx.x;
    const int t = threadIdx.x;

    gsum[t] = 0.0f;                    // NGRP == BLK
    __syncthreads();

    const float4* __restrict__ xrow = (const float4*)(x + (size_t)b * NEUR);
    const int4*   __restrict__ gof  = (const int4*)group_of;

    // Phase 1: coalesced stream of the row, LDS-atomic group accumulation.
    #pragma unroll
    for (int it = 0; it < ITERS; ++it) {
        const int e = it * BLK + t;
        const float4 v = xrow[e];
        const int4 g4 = gof[e];        // 256 KB table, L2-resident
        unsafeAtomicAdd(&gsum[g4.x], v.x);
        unsafeAtomicAdd(&gsum[g4.y], v.y);
        unsafeAtomicAdd(&gsum[g4.z], v.z);
        unsafeAtomicAdd(&gsum[g4.w], v.w);
    }
    __syncthreads();

    // Each thread owns exactly one group entry: in-place reciprocal.
    gsum[t] = 1.0f / gsum[t];
    __syncthreads();

    float4* __restrict__ orow = (float4*)(out + (size_t)b * NEUR);

    // Phase 2: re-read the row (L2/L3 hit — just streamed it), scale, store.
    #pragma unroll
    for (int it = 0; it < ITERS; ++it) {
        const int e = it * BLK + t;
        const float4 v = xrow[e];      // cache-hot re-read
        const int4 g4 = gof[e];
        float4 o;
        o.x = v.x * gsum[g4.x];
        o.y = v.y * gsum[g4.y];
        o.z = v.z * gsum[g4.z];
        o.w = v.w * gsum[g4.w];
        orow[e] = o;
    }
}

extern "C" void kernel_launch(void* const* d_in, const int* in_sizes, int n_in,
                              void* d_out, int out_size, void* d_ws, size_t ws_size,
                              hipStream_t stream) {
    const float* x     = (const float*)d_in[0];
    const int*   index = (const int*)d_in[1];
    float*       out   = (float*)d_out;

    int* group_of = (int*)d_ws;        // 256 KB scratch

    build_group_of<<<(NEUR + 255) / 256, 256, 0, stream>>>(index, group_of);
    lateral_norm_kernel<<<BATCH, BLK, 0, stream>>>(x, group_of, out);
}